// Round 1
// baseline (249.724 us; speedup 1.0000x reference)
//
#include <hip/hip_runtime.h>
#include <hip/hip_bf16.h>

// HierarchicalDistanceLoss: per-row log-softmax CE * distance factor, mean.
// B = 1048576 rows, C = 40 classes. Outputs: [0] = total_loss, [1..B] = distance_factor.

#define HDL_B 1048576
#define HDL_C 40
#define HDL_ALPHA 0.5f
#define HDL_BLOCK 256
#define HDL_GRID (HDL_B / HDL_BLOCK)   // 4096, exact

__global__ __launch_bounds__(HDL_BLOCK)
void hdl_main(const float* __restrict__ logits,
              const int* __restrict__ labels,
              const float* __restrict__ dis,
              float* __restrict__ out,      // out[0]=loss (written by finalize), out[1..B]=df
              double* __restrict__ wsum_global) {
    __shared__ float dls[HDL_C * HDL_C];   // 6.4 KB distance matrix
    __shared__ float wpart[HDL_BLOCK / 64];

    // Stage dis_matrix into LDS (coalesced; hits L2/L3 after first block).
    for (int i = threadIdx.x; i < HDL_C * HDL_C; i += HDL_BLOCK)
        dls[i] = dis[i];
    __syncthreads();

    const int row = blockIdx.x * HDL_BLOCK + threadIdx.x;

    // Load the whole row (160 B) into registers via 10 float4 loads.
    // Per-lane stride is 160 B (uncoalesced per-instruction) but each 64 B
    // line is fully consumed by this thread -> HBM traffic stays ideal.
    const float4* rp = reinterpret_cast<const float4*>(logits + (size_t)row * HDL_C);
    float x[HDL_C];
#pragma unroll
    for (int k = 0; k < HDL_C / 4; ++k) {
        float4 t = rp[k];
        x[4 * k + 0] = t.x;
        x[4 * k + 1] = t.y;
        x[4 * k + 2] = t.z;
        x[4 * k + 3] = t.w;
    }

    // max + argmax (first occurrence of max, matching jnp.argmax).
    float m = x[0];
    int pred = 0;
#pragma unroll
    for (int j = 1; j < HDL_C; ++j) {
        bool g = x[j] > m;
        m = g ? x[j] : m;
        pred = g ? j : pred;
    }

    // sum of exp(x - m) in base 2: one v_exp_f32 per element.
    const float L2E = 1.4426950408889634f;
    const float mL = m * L2E;
    float s = 0.0f;
#pragma unroll
    for (int j = 0; j < HDL_C; ++j)
        s += __builtin_amdgcn_exp2f(__builtin_fmaf(x[j], L2E, -mL));

    const int lab = labels[row];
    // Re-load the labeled logit from global (L1 hit: this thread just
    // fetched those lines). Avoids dynamic indexing into the register array
    // which would force a scratch spill.
    const float xl = logits[(size_t)row * HDL_C + lab];

    // ce = m - x_l + ln(s); ln(s) = log2(s) * ln2 via v_log_f32.
    const float ce = (m - xl) + 0.69314718055994531f * __builtin_amdgcn_logf(s);

    const float df = dls[lab * HDL_C + pred] + HDL_ALPHA;
    out[1 + row] = df;

    float val = ce * df;

    // wave64 shuffle reduction
#pragma unroll
    for (int o = 32; o > 0; o >>= 1)
        val += __shfl_down(val, o, 64);
    const int lane = threadIdx.x & 63;
    const int wid = threadIdx.x >> 6;
    if (lane == 0) wpart[wid] = val;
    __syncthreads();
    if (threadIdx.x == 0) {
        float bs = wpart[0] + wpart[1] + wpart[2] + wpart[3];
        atomicAdd(wsum_global, (double)bs);  // f64 atomic, device scope
    }
}

__global__ void hdl_finalize(const double* __restrict__ wsum_global,
                             float* __restrict__ out) {
    out[0] = (float)(wsum_global[0] * (1.0 / (double)HDL_B));
}

extern "C" void kernel_launch(void* const* d_in, const int* in_sizes, int n_in,
                              void* d_out, int out_size, void* d_ws, size_t ws_size,
                              hipStream_t stream) {
    const float* logits = (const float*)d_in[0];
    const int*   labels = (const int*)d_in[1];
    const float* dis    = (const float*)d_in[2];
    float* out = (float*)d_out;
    double* wsum = (double*)d_ws;

    // ws is re-poisoned to 0xAA before every timed launch — zero the accumulator.
    hipMemsetAsync(wsum, 0, sizeof(double), stream);

    hdl_main<<<HDL_GRID, HDL_BLOCK, 0, stream>>>(logits, labels, dis, out, wsum);
    hdl_finalize<<<1, 1, 0, stream>>>(wsum, out);
}

// Round 2
// 237.720 us; speedup vs baseline: 1.0505x; 1.0505x over previous
//
#include <hip/hip_runtime.h>
#include <hip/hip_bf16.h>

// HierarchicalDistanceLoss: per-row log-softmax CE * distance factor, mean.
// B = 1048576 rows, C = 40 classes (fp32).
// Outputs: out[0] = total_loss, out[1..B] = distance_factor.
//
// R2: coalesced global->LDS staging + transpose (R1's per-thread 160B-stride
// loads were L1-transaction-bound: 64 lines per vmem instr). Two 128-row
// phases per block keep LDS at 21 KB (~7 blocks/CU). Block partial sums to
// d_ws + deterministic finalize (no atomics, no memset node).

#define HDL_B 1048576
#define HDL_C 40
#define HDL_ALPHA 0.5f
#define HDL_BLOCK 256
#define HDL_ROWS 256                    // rows per block
#define HDL_GRID (HDL_B / HDL_ROWS)     // 4096, exact
#define HDL_HALF 128                    // rows per staging phase
#define HDL_PAD 41                      // LDS row stride: gcd(41,32)=1 -> conflict-free row reads

__global__ __launch_bounds__(HDL_BLOCK)
void hdl_main(const float* __restrict__ logits,
              const int* __restrict__ labels,
              const float* __restrict__ dis,
              float* __restrict__ out,          // out[1..B] = df
              float* __restrict__ bsum) {       // d_ws: one float per block
    __shared__ float tile[HDL_HALF * HDL_PAD];  // 20,992 B
    __shared__ float wpart[HDL_BLOCK / 64];

    const int tid = threadIdx.x;
    const int row = blockIdx.x * HDL_ROWS + tid;

    const int lab = labels[row];                // coalesced, issued early

    // Block's logits viewed as flat float4s: 256 rows * 10 f4/row = 2560 f4.
    const float4* gsrc = reinterpret_cast<const float4*>(logits)
                         + (size_t)blockIdx.x * (HDL_ROWS * HDL_C / 4);

    float x[HDL_C];
    float xl = 0.0f;
    const int myhalf = tid >> 7;                // which phase stages my row
    const int lr_mine = tid & (HDL_HALF - 1);

#pragma unroll
    for (int p = 0; p < 2; ++p) {
        // Coalesced load of 128 rows (1280 float4s): 5 f4 per thread,
        // scattered into the padded LDS tile.
#pragma unroll
        for (int k = 0; k < 5; ++k) {
            const int q = tid + HDL_BLOCK * k;                 // [0,1280)
            float4 v = gsrc[p * (HDL_HALF * HDL_C / 4) + q];
            const int lr = q / 10;                             // local row
            const int c4 = q - lr * 10;                        // f4 within row
            const int off = lr * HDL_PAD + c4 * 4;
            tile[off + 0] = v.x;
            tile[off + 1] = v.y;
            tile[off + 2] = v.z;
            tile[off + 3] = v.w;
        }
        __syncthreads();
        if (myhalf == p) {                      // wave-uniform branch
            const int base = lr_mine * HDL_PAD;
#pragma unroll
            for (int j = 0; j < HDL_C; ++j)
                x[j] = tile[base + j];          // stride-41 lanes: conflict-free
            xl = tile[base + lab];              // labeled logit (avoids dynamic reg index)
        }
        __syncthreads();                        // phase 1 overwrites the tile
    }

    // max + argmax (first occurrence, matching jnp.argmax)
    float m = x[0];
    int pred = 0;
#pragma unroll
    for (int j = 1; j < HDL_C; ++j) {
        const bool g = x[j] > m;
        m = g ? x[j] : m;
        pred = g ? j : pred;
    }

    // sum exp(x - m) in base 2: one v_exp_f32 per element
    const float L2E = 1.4426950408889634f;
    const float mL = m * L2E;
    float s = 0.0f;
#pragma unroll
    for (int j = 0; j < HDL_C; ++j)
        s += __builtin_amdgcn_exp2f(__builtin_fmaf(x[j], L2E, -mL));

    // ce = m - x_l + ln(s)
    const float ce = (m - xl) + 0.69314718055994531f * __builtin_amdgcn_logf(s);

    // distance factor: 6.4 KB table is L1-resident after first touch
    const float df = dis[lab * HDL_C + pred] + HDL_ALPHA;
    out[1 + row] = df;

    float val = ce * df;

    // wave64 shuffle reduction -> block partial
#pragma unroll
    for (int o = 32; o > 0; o >>= 1)
        val += __shfl_down(val, o, 64);
    const int lane = tid & 63;
    const int wid = tid >> 6;
    if (lane == 0) wpart[wid] = val;
    __syncthreads();
    if (tid == 0)
        bsum[blockIdx.x] = wpart[0] + wpart[1] + wpart[2] + wpart[3];
}

// Deterministic reduce of the 4096 block partials (no atomics, f64 accumulate).
__global__ __launch_bounds__(256)
void hdl_finalize(const float* __restrict__ bsum,
                  float* __restrict__ out) {
    __shared__ double dpart[4];
    const int tid = threadIdx.x;
    double v = 0.0;
#pragma unroll
    for (int k = 0; k < HDL_GRID / 256; ++k)    // 16 each
        v += (double)bsum[tid + 256 * k];
#pragma unroll
    for (int o = 32; o > 0; o >>= 1)
        v += __shfl_down(v, o, 64);
    if ((tid & 63) == 0) dpart[tid >> 6] = v;
    __syncthreads();
    if (tid == 0) {
        const double tot = dpart[0] + dpart[1] + dpart[2] + dpart[3];
        out[0] = (float)(tot * (1.0 / (double)HDL_B));
    }
}

extern "C" void kernel_launch(void* const* d_in, const int* in_sizes, int n_in,
                              void* d_out, int out_size, void* d_ws, size_t ws_size,
                              hipStream_t stream) {
    const float* logits = (const float*)d_in[0];
    const int*   labels = (const int*)d_in[1];
    const float* dis    = (const float*)d_in[2];
    float* out  = (float*)d_out;
    float* bsum = (float*)d_ws;   // 4096 floats; fully overwritten every call

    hdl_main<<<HDL_GRID, HDL_BLOCK, 0, stream>>>(logits, labels, dis, out, bsum);
    hdl_finalize<<<1, 256, 0, stream>>>(bsum, out);
}

// Round 3
// 237.062 us; speedup vs baseline: 1.0534x; 1.0028x over previous
//
#include <hip/hip_runtime.h>
#include <hip/hip_bf16.h>

// HierarchicalDistanceLoss: per-row log-softmax CE * distance factor, mean.
// B = 1048576 rows, C = 40 classes (fp32).
// Outputs: out[0] = total_loss, out[1..B] = distance_factor.
//
// R3: software-pipelined staging — all 10 float4 global loads issued before
// any LDS work (one HBM-latency exposure per wave instead of two), and
// column-major LDS tile (col stride 129) making both the scatter writes
// (max 2-way, free per m136) and the row reads (lane-consecutive) bank-
// conflict-free. One fewer barrier. Block partials + deterministic finalize.

#define HDL_B 1048576
#define HDL_C 40
#define HDL_ALPHA 0.5f
#define HDL_BLOCK 256
#define HDL_ROWS 256                    // rows per block
#define HDL_GRID (HDL_B / HDL_ROWS)     // 4096, exact
#define HDL_HALF 128                    // rows per staging phase
#define HDL_CSTR (HDL_HALF + 1)         // 129: column stride in words

__global__ __launch_bounds__(HDL_BLOCK, 5)   // cap 102 VGPRs (est peak ~75), >=20 waves/CU
void hdl_main(const float* __restrict__ logits,
              const int* __restrict__ labels,
              const float* __restrict__ dis,
              float* __restrict__ out,          // out[1..B] = df
              float* __restrict__ bsum) {       // d_ws: one float per block
    __shared__ float tile[HDL_C * HDL_CSTR];    // 20,640 B, column-major [col][local_row]
    __shared__ float wpart[HDL_BLOCK / 64];

    const int tid = threadIdx.x;
    const int row = blockIdx.x * HDL_ROWS + tid;
    const int lab = labels[row];                // coalesced, issued early

    const float4* gsrc = reinterpret_cast<const float4*>(logits)
                         + (size_t)blockIdx.x * (HDL_ROWS * HDL_C / 4);

    // Issue ALL global loads up front: 10 outstanding 16B loads per lane.
    float4 v[5], w[5];
#pragma unroll
    for (int k = 0; k < 5; ++k)
        v[k] = gsrc[tid + HDL_BLOCK * k];                          // phase-0 rows
#pragma unroll
    for (int k = 0; k < 5; ++k)
        w[k] = gsrc[HDL_HALF * HDL_C / 4 + tid + HDL_BLOCK * k];   // phase-1 rows

    float x[HDL_C];
    float xl = 0.0f;
    const int lr_mine = tid & (HDL_HALF - 1);

    // ---- phase 0: scatter rows [0,128) ----
#pragma unroll
    for (int k = 0; k < 5; ++k) {
        const int q = tid + HDL_BLOCK * k;      // [0,1280)
        const int lr = q / 10;                  // local row
        const int c4 = q - lr * 10;             // float4 within row
        const int cb = 4 * c4;                  // starting column
        tile[(cb + 0) * HDL_CSTR + lr] = v[k].x;
        tile[(cb + 1) * HDL_CSTR + lr] = v[k].y;
        tile[(cb + 2) * HDL_CSTR + lr] = v[k].z;
        tile[(cb + 3) * HDL_CSTR + lr] = v[k].w;
    }
    __syncthreads();
    if (tid < HDL_HALF) {                       // wave-uniform
#pragma unroll
        for (int j = 0; j < HDL_C; ++j)
            x[j] = tile[j * HDL_CSTR + lr_mine];    // lanes consecutive: conflict-free
        xl = tile[lab * HDL_CSTR + lr_mine];        // labeled logit
    }
    __syncthreads();

    // ---- phase 1: scatter rows [128,256) ----
#pragma unroll
    for (int k = 0; k < 5; ++k) {
        const int q = tid + HDL_BLOCK * k;
        const int lr = q / 10;
        const int c4 = q - lr * 10;
        const int cb = 4 * c4;
        tile[(cb + 0) * HDL_CSTR + lr] = w[k].x;
        tile[(cb + 1) * HDL_CSTR + lr] = w[k].y;
        tile[(cb + 2) * HDL_CSTR + lr] = w[k].z;
        tile[(cb + 3) * HDL_CSTR + lr] = w[k].w;
    }
    __syncthreads();
    if (tid >= HDL_HALF) {
#pragma unroll
        for (int j = 0; j < HDL_C; ++j)
            x[j] = tile[j * HDL_CSTR + lr_mine];
        xl = tile[lab * HDL_CSTR + lr_mine];
    }
    // no barrier needed: tile is not written again

    // max + argmax (first occurrence, matching jnp.argmax)
    float m = x[0];
    int pred = 0;
#pragma unroll
    for (int j = 1; j < HDL_C; ++j) {
        const bool g = x[j] > m;
        m = g ? x[j] : m;
        pred = g ? j : pred;
    }

    // sum exp(x - m) in base 2: one v_exp_f32 per element
    const float L2E = 1.4426950408889634f;
    const float mL = m * L2E;
    float s = 0.0f;
#pragma unroll
    for (int j = 0; j < HDL_C; ++j)
        s += __builtin_amdgcn_exp2f(__builtin_fmaf(x[j], L2E, -mL));

    // ce = m - x_l + ln(s)
    const float ce = (m - xl) + 0.69314718055994531f * __builtin_amdgcn_logf(s);

    // distance factor: 6.4 KB table is L1-resident after first touch
    const float df = dis[lab * HDL_C + pred] + HDL_ALPHA;
    out[1 + row] = df;

    float val = ce * df;

    // wave64 shuffle reduction -> block partial
#pragma unroll
    for (int o = 32; o > 0; o >>= 1)
        val += __shfl_down(val, o, 64);
    const int lane = tid & 63;
    const int wid = tid >> 6;
    if (lane == 0) wpart[wid] = val;
    __syncthreads();
    if (tid == 0)
        bsum[blockIdx.x] = wpart[0] + wpart[1] + wpart[2] + wpart[3];
}

// Deterministic reduce of the 4096 block partials (no atomics, f64 accumulate).
__global__ __launch_bounds__(256)
void hdl_finalize(const float* __restrict__ bsum,
                  float* __restrict__ out) {
    __shared__ double dpart[4];
    const int tid = threadIdx.x;
    double v = 0.0;
#pragma unroll
    for (int k = 0; k < HDL_GRID / 256; ++k)    // 16 each
        v += (double)bsum[tid + 256 * k];
#pragma unroll
    for (int o = 32; o > 0; o >>= 1)
        v += __shfl_down(v, o, 64);
    if ((tid & 63) == 0) dpart[tid >> 6] = v;
    __syncthreads();
    if (tid == 0) {
        const double tot = dpart[0] + dpart[1] + dpart[2] + dpart[3];
        out[0] = (float)(tot * (1.0 / (double)HDL_B));
    }
}

extern "C" void kernel_launch(void* const* d_in, const int* in_sizes, int n_in,
                              void* d_out, int out_size, void* d_ws, size_t ws_size,
                              hipStream_t stream) {
    const float* logits = (const float*)d_in[0];
    const int*   labels = (const int*)d_in[1];
    const float* dis    = (const float*)d_in[2];
    float* out  = (float*)d_out;
    float* bsum = (float*)d_ws;   // 4096 floats; fully overwritten every call

    hdl_main<<<HDL_GRID, HDL_BLOCK, 0, stream>>>(logits, labels, dis, out, bsum);
    hdl_finalize<<<1, 256, 0, stream>>>(bsum, out);
}